// Round 2
// baseline (23.675 us; speedup 1.0000x reference)
//
#include <hip/hip_runtime.h>

// SeeSawLoss, simplified:
//   loss(b,h,w) = log( sum_i exp(l[b,i,h,w]) * max(w[b,i], w[b,t]) ) - log(w[b,t]) - l[b,t,h,w]
//   out = mean over all (b,h,w)
// since M[i,t] = (wi > wt ? wi/wt : 1) == max(wi, wt)/wt.
// B=8, N=128, H=W=128.

#define B_    8
#define N_    128
#define HW_   16384              // 128*128
#define NPIX  (B_ * HW_)         // 131072
#define BLOCK 64                 // one wave per block
#define PPT   4                  // pixels per thread (float4)
#define PIX_PER_BLOCK (BLOCK * PPT)          // 256
#define BLOCKS_PER_B  (HW_ / PIX_PER_BLOCK)  // 64
#define NBLOCKS (B_ * BLOCKS_PER_B)          // 512

__global__ __launch_bounds__(BLOCK) void seesaw_main(
    const float* __restrict__ logit,
    const int*   __restrict__ target,
    const float* __restrict__ weight,
    float*       __restrict__ partials)
{
    __shared__ float w_s[N_];

    const int b    = blockIdx.x >> 6;                       // / BLOCKS_PER_B
    const int pix0 = (blockIdx.x & 63) * PIX_PER_BLOCK + threadIdx.x * PPT;

    w_s[threadIdx.x]      = weight[b * N_ + threadIdx.x];
    w_s[threadIdx.x + 64] = weight[b * N_ + threadIdx.x + 64];
    __syncthreads();

    const int4 t4 = *(const int4*)(target + b * HW_ + pix0);

    const float wt0 = w_s[t4.x], wt1 = w_s[t4.y], wt2 = w_s[t4.z], wt3 = w_s[t4.w];
    const float lw0 = __logf(wt0), lw1 = __logf(wt1), lw2 = __logf(wt2), lw3 = __logf(wt3);

    const float* lp = logit + (size_t)b * N_ * HW_ + pix0;

    float a0 = 0.f, a1 = 0.f, a2 = 0.f, a3 = 0.f;   // denominators
    float l0 = 0.f, l1 = 0.f, l2 = 0.f, l3 = 0.f;   // logit at target

    #pragma unroll 16
    for (int i = 0; i < N_; ++i) {
        const float4 l = *(const float4*)(lp + (size_t)i * HW_);
        const float wi = w_s[i];
        a0 = fmaf(__expf(l.x), fmaxf(wi, wt0), a0);
        a1 = fmaf(__expf(l.y), fmaxf(wi, wt1), a1);
        a2 = fmaf(__expf(l.z), fmaxf(wi, wt2), a2);
        a3 = fmaf(__expf(l.w), fmaxf(wi, wt3), a3);
        l0 = (i == t4.x) ? l.x : l0;
        l1 = (i == t4.y) ? l.y : l1;
        l2 = (i == t4.z) ? l.z : l2;
        l3 = (i == t4.w) ? l.w : l3;
    }

    float loss = (__logf(a0) - lw0 - l0)
               + (__logf(a1) - lw1 - l1)
               + (__logf(a2) - lw2 - l2)
               + (__logf(a3) - lw3 - l3);

    // single-wave reduction
    #pragma unroll
    for (int o = 32; o > 0; o >>= 1) loss += __shfl_down(loss, o, 64);

    if (threadIdx.x == 0) partials[blockIdx.x] = loss;
}

__global__ __launch_bounds__(512) void seesaw_reduce(
    const float* __restrict__ partials,
    float*       __restrict__ out)
{
    __shared__ float red[8];
    float s = partials[threadIdx.x];

    #pragma unroll
    for (int o = 32; o > 0; o >>= 1) s += __shfl_down(s, o, 64);

    const int lane = threadIdx.x & 63;
    const int wid  = threadIdx.x >> 6;
    if (lane == 0) red[wid] = s;
    __syncthreads();

    if (threadIdx.x == 0) {
        float tot = 0.f;
        #pragma unroll
        for (int k = 0; k < 8; ++k) tot += red[k];
        out[0] = tot * (1.0f / (float)NPIX);
    }
}

extern "C" void kernel_launch(void* const* d_in, const int* in_sizes, int n_in,
                              void* d_out, int out_size, void* d_ws, size_t ws_size,
                              hipStream_t stream)
{
    const float* logit  = (const float*)d_in[0];
    const int*   target = (const int*)  d_in[1];
    const float* weight = (const float*)d_in[2];
    // d_in[3] = epoch (unused by the reference math)

    float* partials = (float*)d_ws;   // NBLOCKS floats
    float* out      = (float*)d_out;

    seesaw_main<<<NBLOCKS, BLOCK, 0, stream>>>(logit, target, weight, partials);
    seesaw_reduce<<<1, 512, 0, stream>>>(partials, out);
}

// Round 3
// 18.397 us; speedup vs baseline: 1.2869x; 1.2869x over previous
//
#include <hip/hip_runtime.h>

// SeeSawLoss, simplified:
//   loss(b,h,w) = log( sum_i exp(l[b,i,h,w]) * max(w[b,i], w[b,t]) ) - log(w[b,t]) - l[b,t,h,w]
//   out = mean over all (b,h,w)
// since M[i,t] = (wi > wt ? wi/wt : 1) == max(wi, wt)/wt.
// B=8, N=128, H=W=128.
//
// Parallelization: 2 threads per pixel (class-halves 0-63 / 64-127), combined
// via LDS. 1024 blocks x 256 threads = 16 waves/CU (R2 lesson: wave count
// dominates per-wave ILP for this latency-bound stream).

#define B_    8
#define N_    128
#define HALF_N 64
#define HW_   16384              // 128*128
#define NPIX  (B_ * HW_)         // 131072
#define BLOCK 256
#define PIX_PER_BLOCK 128        // 2 threads per pixel
#define BLOCKS_PER_B  (HW_ / PIX_PER_BLOCK)  // 128
#define NBLOCKS (B_ * BLOCKS_PER_B)          // 1024

__global__ __launch_bounds__(BLOCK) void seesaw_main(
    const float* __restrict__ logit,
    const int*   __restrict__ target,
    const float* __restrict__ weight,
    float*       __restrict__ partials)
{
    __shared__ float w_s[N_];
    __shared__ float sa[PIX_PER_BLOCK];
    __shared__ float sl[PIX_PER_BLOCK];
    __shared__ float red[BLOCK / 64];

    const int b    = blockIdx.x >> 7;               // / BLOCKS_PER_B
    const int pl   = threadIdx.x & 127;             // pixel-local index
    const int half = threadIdx.x >> 7;              // class-half 0/1
    const int pix  = (blockIdx.x & 127) * PIX_PER_BLOCK + pl;

    if (threadIdx.x < N_) w_s[threadIdx.x] = weight[b * N_ + threadIdx.x];
    __syncthreads();

    const int   t  = target[b * HW_ + pix];
    const float wt = w_s[t];

    const float* lp = logit + (size_t)b * N_ * HW_ + (size_t)half * HALF_N * HW_ + pix;
    const int ibase = half * HALF_N;

    float a  = 0.0f;   // partial denom over this half's classes
    float lt = 0.0f;   // logit at target class (0 if t not in this half)

    #pragma unroll 16
    for (int k = 0; k < HALF_N; ++k) {
        const float l  = lp[(size_t)k * HW_];
        const float wi = w_s[ibase + k];
        a  = fmaf(__expf(l), fmaxf(wi, wt), a);
        lt = (ibase + k == t) ? l : lt;
    }

    if (half) { sa[pl] = a; sl[pl] = lt; }
    __syncthreads();

    float loss = 0.0f;
    if (!half) {
        const float at = a + sa[pl];
        const float lf = lt + sl[pl];
        loss = __logf(at) - __logf(wt) - lf;
    }

    // wave reduction (waves 2,3 carry zeros)
    #pragma unroll
    for (int o = 32; o > 0; o >>= 1) loss += __shfl_down(loss, o, 64);

    const int lane = threadIdx.x & 63;
    const int wid  = threadIdx.x >> 6;
    if (lane == 0) red[wid] = loss;
    __syncthreads();

    if (threadIdx.x == 0) {
        float s = 0.0f;
        #pragma unroll
        for (int k = 0; k < BLOCK / 64; ++k) s += red[k];
        partials[blockIdx.x] = s;
    }
}

__global__ __launch_bounds__(1024) void seesaw_reduce(
    const float* __restrict__ partials,
    float*       __restrict__ out)
{
    __shared__ float red[16];
    float s = partials[threadIdx.x];

    #pragma unroll
    for (int o = 32; o > 0; o >>= 1) s += __shfl_down(s, o, 64);

    const int lane = threadIdx.x & 63;
    const int wid  = threadIdx.x >> 6;
    if (lane == 0) red[wid] = s;
    __syncthreads();

    if (threadIdx.x == 0) {
        float tot = 0.0f;
        #pragma unroll
        for (int k = 0; k < 16; ++k) tot += red[k];
        out[0] = tot * (1.0f / (float)NPIX);
    }
}

extern "C" void kernel_launch(void* const* d_in, const int* in_sizes, int n_in,
                              void* d_out, int out_size, void* d_ws, size_t ws_size,
                              hipStream_t stream)
{
    const float* logit  = (const float*)d_in[0];
    const int*   target = (const int*)  d_in[1];
    const float* weight = (const float*)d_in[2];
    // d_in[3] = epoch (unused by the reference math)

    float* partials = (float*)d_ws;   // NBLOCKS floats
    float* out      = (float*)d_out;

    seesaw_main<<<NBLOCKS, BLOCK, 0, stream>>>(logit, target, weight, partials);
    seesaw_reduce<<<1, 1024, 0, stream>>>(partials, out);
}